// Round 20
// baseline (221.901 us; speedup 1.0000x reference)
//
#include <hip/hip_runtime.h>
#include <hip/hip_bf16.h>
#include <stdint.h>

#define TOKENS 8192
#define IN_F   4096
#define OUT_F  4096
#define GROUP  128

typedef __attribute__((ext_vector_type(4))) int   i32x4;
typedef __attribute__((ext_vector_type(4))) float f32x4;

// ---------------------------------------------------------------------------
// Kernel 1 (fused prep): blocks 0..255 requantize W (VALU-bound);
// blocks 256..8447 quantize x rows (HBM-bound). Independent work -> one
// dispatch; VALU work hides under the HBM stream.
// ---------------------------------------------------------------------------
__global__ __launch_bounds__(256) void k_prep(
    const float* __restrict__ x, int8_t* __restrict__ xq,
    float* __restrict__ xs, const int* __restrict__ qweight,
    const int* __restrict__ qzeros, const float* __restrict__ scales,
    int8_t* __restrict__ wq, float* __restrict__ sw) {
  __shared__ float smax[16][17];  // requant reduce
  __shared__ float red[4];        // quant reduce
  const int bid = blockIdx.x;
  const int t = threadIdx.x;

  if (bid < 256) {
    // ---- requant: Sw[n] = max_g s_g[n]*max(z_g,15-z_g)/127 (no clip);
    //      wq[n][k] = round(s_g*(w-z_g)/Sw[n]) in [-127,127]
    const int n0 = bid * 16;
    const int col = t & 15;
    const int seg = t >> 4;  // 0..15, 2 groups each
    const int n = n0 + col;

    int zloc[2];
    float sloc[2];
    float m = 0.f;
#pragma unroll
    for (int i = 0; i < 2; ++i) {
      const int g = seg * 2 + i;
      const unsigned zw =
          ((const unsigned*)qzeros)[(size_t)g * (OUT_F / 8) + (n >> 3)];
      const int z = (int)((zw >> ((n & 7) * 4)) & 15u);
      const float s = scales[(size_t)g * OUT_F + n];
      zloc[i] = z;
      sloc[i] = s;
      m = fmaxf(m, s * (float)(z > 15 - z ? z : 15 - z));
    }
    smax[col][seg] = m;
    __syncthreads();
    float Sw = 0.f;
#pragma unroll
    for (int ss = 0; ss < 16; ++ss) Sw = fmaxf(Sw, smax[col][ss]);
    Sw /= 127.f;  // > 0 always
    if (seg == 0) sw[n] = Sw;
    const float inv = 1.f / Sw;

#pragma unroll
    for (int i = 0; i < 2; ++i) {
      const int g = seg * 2 + i;
      const int z = zloc[i];
      const float f = sloc[i] * inv;
#pragma unroll
      for (int kw = 0; kw < 16; ++kw) {
        const unsigned w =
            ((const unsigned*)qweight)[(size_t)(g * 16 + kw) * OUT_F + n];
        unsigned lo = 0, hi = 0;
#pragma unroll
        for (int j = 0; j < 8; ++j) {
          const int q = (int)((w >> (4 * j)) & 15u);
          const int v = __float2int_rn(f * (float)(q - z));
          const unsigned b = (unsigned)(v & 255);
          if (j < 4)
            lo |= b << (8 * j);
          else
            hi |= b << (8 * (j - 4));
        }
        uint2 pk = {lo, hi};
        *(uint2*)(wq + (size_t)n * IN_F + (size_t)(g * 16 + kw) * 8) = pk;
      }
    }
  } else {
    // ---- quant_x: per-token absmax scale, x ~ xs[m]*xq
    const int row = bid - 256;
    const float4* xr = (const float4*)(x + (size_t)row * IN_F) + t * 4;
    float f[16];
    *(float4*)&f[0] = xr[0];
    *(float4*)&f[4] = xr[1];
    *(float4*)&f[8] = xr[2];
    *(float4*)&f[12] = xr[3];
    float am = 0.f;
#pragma unroll
    for (int j = 0; j < 16; ++j) am = fmaxf(am, fabsf(f[j]));
#pragma unroll
    for (int off = 32; off; off >>= 1) am = fmaxf(am, __shfl_xor(am, off));
    if ((t & 63) == 0) red[t >> 6] = am;
    __syncthreads();
    am = fmaxf(fmaxf(red[0], red[1]), fmaxf(red[2], red[3]));
    am = fmaxf(am, 1e-8f);
    const float inv = 127.f / am;
    if (t == 0) xs[row] = am / 127.f;
    union {
      i32x4 v;
      int8_t c[16];
    } u;
#pragma unroll
    for (int j = 0; j < 16; ++j) u.c[j] = (int8_t)__float2int_rn(f[j] * inv);
    ((i32x4*)(xq + (size_t)row * IN_F))[t] = u.v;
  }
}

// ---------------------------------------------------------------------------
// Kernel 2: PURE int8 MFMA GEMM. Round-20: 3 blocks/CU.
// Block 128x128, 4 waves (2x2), wave 64x64, BK=64.
// LDS = 2 bufs x (A 8K + B 8K) = 32 KB -> 3 blocks/CU (96 KB; regs
// 3 x ~148 = 444 <= 512, launch_bounds(256,3)). Total LDS traffic is
// unchanged vs BK=128 (perimeter economics); the 3rd unsynchronized block
// overlays the barrier/drain gaps (r19 measured 80% LDS-pipe utilization;
// floor ~109 us).
// Swizzle sigma(r) = (r>>1)&3 (r18-verified, 0 conflicts): slot s of row r
// holds global chunk s ^ sigma(r); fragment read slot = hq ^ ((fr>>1)&3).
// Per phase (round-11 WAR invariant): 8 ds_reads -> lgkm(0) -> barrier ->
// STAGE T+2 (same buf, 4 gloads/thr) -> 16 MFMA -> vmcnt(4) -> barrier.
// XCD map: xcd owns 4 bn (512 cols, 2 MB B-slice L2-resident); bm streams.
// Epilogue: out = xs[m]*Sw[n]*acc + bias[n].
// ---------------------------------------------------------------------------
__device__ inline void gload_lds16(const void* g, void* l) {
  __builtin_amdgcn_global_load_lds(
      (const __attribute__((address_space(1))) void*)g,
      (__attribute__((address_space(3))) void*)l, 16, 0, 0);
}

#define STAGE_T(buf, tile)                                                    \
  do {                                                                        \
    _Pragma("unroll") for (int r_ = 0; r_ < 2; ++r_) {                        \
      gload_lds16(Ag + goffS[r_] + (size_t)((tile) & 63) * 64,                \
                  smem + (buf)*16384 + ldsS[r_]);                             \
    }                                                                         \
    _Pragma("unroll") for (int r_ = 0; r_ < 2; ++r_) {                        \
      gload_lds16(Bg + goffS[r_] + (size_t)((tile) & 63) * 64,                \
                  smem + (buf)*16384 + 8192 + ldsS[r_]);                      \
    }                                                                         \
  } while (0)

#define PHASE(bufc, T)                                                        \
  do {                                                                        \
    const char* aB_ = smem + (bufc)*16384 + (wr * 64 + fr) * 64;              \
    const char* bB_ = smem + (bufc)*16384 + 8192 + (wc * 64 + fr) * 64;       \
    _Pragma("unroll") for (int mf_ = 0; mf_ < 4; ++mf_) {                     \
      aF[mf_] = *(const i32x4*)(aB_ + mf_ * 1024 + csw);                      \
    }                                                                         \
    _Pragma("unroll") for (int nf_ = 0; nf_ < 4; ++nf_) {                     \
      bF[nf_] = *(const i32x4*)(bB_ + nf_ * 1024 + csw);                      \
    }                                                                         \
    asm volatile("s_waitcnt lgkmcnt(0)" ::: "memory");                        \
    __builtin_amdgcn_sched_barrier(0);                                        \
    __builtin_amdgcn_s_barrier(); /* all waves' reads of bufc done */         \
    STAGE_T(bufc, (T) + 2);       /* safe to overwrite bufc now */            \
    __builtin_amdgcn_s_setprio(1);                                            \
    _Pragma("unroll") for (int nf_ = 0; nf_ < 4; ++nf_)                       \
        _Pragma("unroll") for (int mf_ = 0; mf_ < 4; ++mf_) {                 \
      iacc[mf_][nf_] = __builtin_amdgcn_mfma_i32_16x16x64_i8(                 \
          aF[mf_], bF[nf_], iacc[mf_][nf_], 0, 0, 0);                         \
    }                                                                         \
    __builtin_amdgcn_s_setprio(0);                                            \
    __builtin_amdgcn_sched_barrier(0);                                        \
    asm volatile("s_waitcnt vmcnt(4)" ::: "memory");                          \
    __builtin_amdgcn_s_barrier();                                             \
  } while (0)

__global__ __launch_bounds__(256, 3) void k_gemm_i8(
    const int8_t* __restrict__ xq,   // [TOKENS][IN_F]
    const int8_t* __restrict__ wq,   // [OUT_F][IN_F]
    const float* __restrict__ sw,    // [OUT_F]
    const float* __restrict__ xs,    // [TOKENS]
    const float* __restrict__ bias,  // [OUT_F]
    float* __restrict__ out) {       // [TOKENS][OUT_F]
  extern __shared__ __align__(16) char smem[];  // 32768 B

  // XCD map: xcd OWNS bn range xcd*4..+3 (512 cols, 2 MB B-slice);
  // bm sweeps slowly (4 consecutive slots share each A-panel via L2).
  const int bidx = blockIdx.x;
  const int xcd = bidx & 7;
  const int slot = bidx >> 3;           // 0..255
  const int bm = slot >> 2;             // 0..63
  const int bn = xcd * 4 + (slot & 3);  // 0..31
  const int m0 = bm * 128;
  const int n0 = bn * 128;

  const int t = threadIdx.x;
  const int lane = t & 63;
  const int wid = t >> 6;    // 4 waves
  const int wr = wid >> 1;   // 2 (M)
  const int wc = wid & 1;    // 2 (N)
  const int fr = lane & 15;
  const int hq = lane >> 4;  // k-quarter (16 int8 = lane's K-slice)

  // sigma(r) = (r>>1)&3 swizzle; fragment read slot = hq ^ ((fr>>1)&3).
  const int csw = (hq ^ ((fr >> 1) & 3)) * 16;

  // staging: each of A,B = 128 rows x 64 B = 512 chunks; 256 thr x 2.
  int goffS[2], ldsS[2];
#pragma unroll
  for (int r = 0; r < 2; ++r) {
    const int c = r * 256 + t;
    const int srow = c >> 2;                      // 0..127
    const int sch = (c & 3) ^ ((srow >> 1) & 3);  // inverse swizzle
    goffS[r] = srow * IN_F + sch * 16;
    ldsS[r] = (r * 256 + wid * 64) * 16;          // wave-uniform base
  }

  const char* Ag = (const char*)(xq + (size_t)m0 * IN_F);
  const char* Bg = (const char*)(wq + (size_t)n0 * IN_F);

  i32x4 iacc[4][4];
#pragma unroll
  for (int i = 0; i < 4; ++i)
#pragma unroll
    for (int j = 0; j < 4; ++j) iacc[i][j] = (i32x4){0, 0, 0, 0};

  i32x4 aF[4];
  i32x4 bF[4];

  // ---- prologue: stage tiles 0 (buf0), 1 (buf1); drain tile0.
  STAGE_T(0, 0);
  STAGE_T(1, 1);
  asm volatile("s_waitcnt vmcnt(4) lgkmcnt(0)" ::: "memory");
  __builtin_amdgcn_s_barrier();

  // ---- main loop: 64 K-tiles (K=64 each), bufs alternate.
#pragma unroll 1
  for (int it = 0; it < 32; ++it) {
    const int T = 2 * it;
    PHASE(0, T);
    PHASE(1, T + 1);
  }

  // ---- epilogue: out = xs[m]*Sw[n]*acc + bias[n]
  float swv[4], bv[4];
#pragma unroll
  for (int nf = 0; nf < 4; ++nf) {
    const int n = n0 + wc * 64 + nf * 16 + fr;
    swv[nf] = sw[n];
    bv[nf] = bias[n];
  }
#pragma unroll
  for (int mf = 0; mf < 4; ++mf) {
#pragma unroll
    for (int r = 0; r < 4; ++r) {
      const int m = m0 + wr * 64 + mf * 16 + hq * 4 + r;
      const float xsv = xs[m];
      float* o = out + (size_t)m * OUT_F + n0;
#pragma unroll
      for (int nf = 0; nf < 4; ++nf) {
        o[wc * 64 + nf * 16 + fr] =
            xsv * swv[nf] * (float)iacc[mf][nf][r] + bv[nf];
      }
    }
  }
}

// ---------------------------------------------------------------------------
extern "C" void kernel_launch(void* const* d_in, const int* in_sizes, int n_in,
                              void* d_out, int out_size, void* d_ws,
                              size_t ws_size, hipStream_t stream) {
  const float* x = (const float*)d_in[0];
  const int* qweight = (const int*)d_in[1];
  const int* qzeros = (const int*)d_in[2];
  const float* scales = (const float*)d_in[3];
  const float* bias = (const float*)d_in[4];
  float* out = (float*)d_out;

  int8_t* xq = (int8_t*)d_ws;                       // 32 MiB
  int8_t* wq = xq + (size_t)TOKENS * IN_F;          // +16 MiB
  float* xs = (float*)(wq + (size_t)OUT_F * IN_F);  // +32 KiB
  float* sw = xs + TOKENS;                          // +16 KiB

  (void)hipFuncSetAttribute(reinterpret_cast<const void*>(&k_gemm_i8),
                            hipFuncAttributeMaxDynamicSharedMemorySize, 32768);

  // fused prep: 256 requant blocks (first) + 8192 quant blocks, concurrent
  k_prep<<<256 + TOKENS, 256, 0, stream>>>(x, xq, xs, qweight, qzeros, scales,
                                           wq, sw);
  k_gemm_i8<<<(TOKENS / 128) * (OUT_F / 128), 256, 32768, stream>>>(
      xq, wq, sw, xs, bias, out);
}

// Round 21
// 192.075 us; speedup vs baseline: 1.1553x; 1.1553x over previous
//
#include <hip/hip_runtime.h>
#include <hip/hip_bf16.h>
#include <stdint.h>

#define TOKENS 8192
#define IN_F   4096
#define OUT_F  4096
#define GROUP  128

typedef __attribute__((ext_vector_type(4))) int   i32x4;
typedef __attribute__((ext_vector_type(4))) float f32x4;

// ---------------------------------------------------------------------------
// Kernel 1 (fused prep): blocks 0..255 requantize W (VALU-bound, now with
// LDS-transposed COALESCED wq writes); blocks 256..8447 quantize x rows
// (HBM-bound). Independent work -> one dispatch.
// Requant r21 fix: old path wrote 8 B/lane at stride 4096 (adjacent lanes =
// adjacent n-cols) -> 4-8x HBM write amplification on 16 MB. Now stage
// 16 cols x 2048 k per pass in LDS (row stride 2064 = +16B pad) and write
// out row-wise: 16 lanes x 16 B contiguous = 256 B runs.
// ---------------------------------------------------------------------------
__global__ __launch_bounds__(256) void k_prep(
    const float* __restrict__ x, int8_t* __restrict__ xq,
    float* __restrict__ xs, const int* __restrict__ qweight,
    const int* __restrict__ qzeros, const float* __restrict__ scales,
    int8_t* __restrict__ wq, float* __restrict__ sw) {
  extern __shared__ __align__(16) char tile[];  // 33024 B (requant staging)
  __shared__ float smax[16][17];                // requant reduce
  __shared__ float red[4];                      // quant reduce
  const int bid = blockIdx.x;
  const int t = threadIdx.x;

  if (bid < 256) {
    // ---- requant: Sw[n] = max_g s_g[n]*max(z_g,15-z_g)/127 (no clip);
    //      wq[n][k] = round(s_g*(w-z_g)/Sw[n]) in [-127,127]
    const int n0 = bid * 16;
    const int col = t & 15;
    const int seg = t >> 4;  // 0..15
    const int n = n0 + col;

    // Sw = column max over all 32 groups (seg covers groups 2seg, 2seg+1)
    float m = 0.f;
#pragma unroll
    for (int i = 0; i < 2; ++i) {
      const int g = seg * 2 + i;
      const unsigned zw =
          ((const unsigned*)qzeros)[(size_t)g * (OUT_F / 8) + (n >> 3)];
      const int z = (int)((zw >> ((n & 7) * 4)) & 15u);
      const float s = scales[(size_t)g * OUT_F + n];
      m = fmaxf(m, s * (float)(z > 15 - z ? z : 15 - z));
    }
    smax[col][seg] = m;
    __syncthreads();
    float Sw = 0.f;
#pragma unroll
    for (int ss = 0; ss < 16; ++ss) Sw = fmaxf(Sw, smax[col][ss]);
    Sw /= 127.f;  // > 0 always
    if (seg == 0) sw[n] = Sw;
    const float inv = 1.f / Sw;

    // two passes of 16 groups (2048 k) each: compute -> LDS -> coalesced out
#pragma unroll
    for (int p = 0; p < 2; ++p) {
      const int g = p * 16 + seg;
      const unsigned zw =
          ((const unsigned*)qzeros)[(size_t)g * (OUT_F / 8) + (n >> 3)];
      const int z = (int)((zw >> ((n & 7) * 4)) & 15u);
      const float f = scales[(size_t)g * OUT_F + n] * inv;
#pragma unroll
      for (int kw = 0; kw < 16; ++kw) {
        const unsigned w =
            ((const unsigned*)qweight)[(size_t)(g * 16 + kw) * OUT_F + n];
        unsigned lo = 0, hi = 0;
#pragma unroll
        for (int j = 0; j < 8; ++j) {
          const int q = (int)((w >> (4 * j)) & 15u);
          const int v = __float2int_rn(f * (float)(q - z));
          const unsigned b = (unsigned)(v & 255);
          if (j < 4)
            lo |= b << (8 * j);
          else
            hi |= b << (8 * (j - 4));
        }
        uint2 pk = {lo, hi};
        *(uint2*)(tile + col * 2064 + seg * 128 + kw * 8) = pk;
      }
      __syncthreads();
      // coalesced write-out: row = t>>4, j = t&15; 128 B per thread
      {
        const int row = t >> 4;
        const int j = t & 15;
        int8_t* dst = wq + (size_t)(n0 + row) * IN_F + p * 2048 + j * 128;
        const char* src = tile + row * 2064 + j * 128;
#pragma unroll
        for (int i = 0; i < 8; ++i) {
          *(i32x4*)(dst + i * 16) = *(const i32x4*)(src + i * 16);
        }
      }
      __syncthreads();
    }
  } else {
    // ---- quant_x: per-token absmax scale, x ~ xs[m]*xq
    const int row = bid - 256;
    const float4* xr = (const float4*)(x + (size_t)row * IN_F) + t * 4;
    float f[16];
    *(float4*)&f[0] = xr[0];
    *(float4*)&f[4] = xr[1];
    *(float4*)&f[8] = xr[2];
    *(float4*)&f[12] = xr[3];
    float am = 0.f;
#pragma unroll
    for (int j = 0; j < 16; ++j) am = fmaxf(am, fabsf(f[j]));
#pragma unroll
    for (int off = 32; off; off >>= 1) am = fmaxf(am, __shfl_xor(am, off));
    if ((t & 63) == 0) red[t >> 6] = am;
    __syncthreads();
    am = fmaxf(fmaxf(red[0], red[1]), fmaxf(red[2], red[3]));
    am = fmaxf(am, 1e-8f);
    const float inv = 127.f / am;
    if (t == 0) xs[row] = am / 127.f;
    union {
      i32x4 v;
      int8_t c[16];
    } u;
#pragma unroll
    for (int j = 0; j < 16; ++j) u.c[j] = (int8_t)__float2int_rn(f[j] * inv);
    ((i32x4*)(xq + (size_t)row * IN_F))[t] = u.v;
  }
}

// ---------------------------------------------------------------------------
// Kernel 2: PURE int8 MFMA GEMM — round-15/19 configuration (measured best:
// 135-137 us, MfmaUtil ~48-51, 0 bank conflicts). Structural sweep complete:
// r14 166 / r16 143.6 / r17 165.7 / r18 151 / r20 177.5 all worse.
// Block 128x128, 4 waves (2x2), wave tile 64x64, BK=128.
// LDS = 2 bufs x (A16K + B16K) = 64 KB -> 2 blocks/CU; regs ~148/wave.
// Per phase (WAR invariant): 16 ds_reads -> lgkm(0) -> barrier ->
// STAGE T+2 (same buf) -> 32 MFMA -> vmcnt(8) -> barrier.
// XCD map: xcd owns 4 bn (512 cols, 2 MB B-slice L2-resident); bm streams.
// Epilogue: out = xs[m]*Sw[n]*acc + bias[n].
// ---------------------------------------------------------------------------
__device__ inline void gload_lds16(const void* g, void* l) {
  __builtin_amdgcn_global_load_lds(
      (const __attribute__((address_space(1))) void*)g,
      (__attribute__((address_space(3))) void*)l, 16, 0, 0);
}

#define STAGE_T(buf, tile)                                                    \
  do {                                                                        \
    _Pragma("unroll") for (int i_ = 0; i_ < 4; ++i_) {                        \
      gload_lds16(Ag + goffS[i_] + (size_t)((tile) & 31) * 128,               \
                  smem + (buf)*32768 + ldsS[i_]);                             \
    }                                                                         \
    _Pragma("unroll") for (int i_ = 0; i_ < 4; ++i_) {                        \
      gload_lds16(Bg + goffS[i_] + (size_t)((tile) & 31) * 128,               \
                  smem + (buf)*32768 + 16384 + ldsS[i_]);                     \
    }                                                                         \
  } while (0)

#define PHASE(bufc, T)                                                        \
  do {                                                                        \
    _Pragma("unroll") for (int nf_ = 0; nf_ < 4; ++nf_) {                     \
      const char* p_ =                                                        \
          smem + (bufc)*32768 + 16384 + (wc * 64 + nf_ * 16 + fr) * 128;      \
      bF[nf_][0] = *(const i32x4*)(p_ + csw0);                                \
      bF[nf_][1] = *(const i32x4*)(p_ + csw1);                                \
    }                                                                         \
    _Pragma("unroll") for (int mf_ = 0; mf_ < 4; ++mf_) {                     \
      const char* p_ = smem + (bufc)*32768 + (wr * 64 + mf_ * 16 + fr) * 128; \
      aF[mf_][0] = *(const i32x4*)(p_ + csw0);                                \
      aF[mf_][1] = *(const i32x4*)(p_ + csw1);                                \
    }                                                                         \
    asm volatile("s_waitcnt lgkmcnt(0)" ::: "memory");                        \
    __builtin_amdgcn_sched_barrier(0);                                        \
    __builtin_amdgcn_s_barrier(); /* all waves' reads of bufc done */         \
    STAGE_T(bufc, (T) + 2);       /* safe to overwrite bufc now */            \
    __builtin_amdgcn_s_setprio(1);                                            \
    _Pragma("unroll") for (int nf_ = 0; nf_ < 4; ++nf_)                       \
        _Pragma("unroll") for (int mf_ = 0; mf_ < 4; ++mf_) {                 \
      iacc[mf_][nf_] = __builtin_amdgcn_mfma_i32_16x16x64_i8(                 \
          aF[mf_][0], bF[nf_][0], iacc[mf_][nf_], 0, 0, 0);                   \
    }                                                                         \
    _Pragma("unroll") for (int nf_ = 0; nf_ < 4; ++nf_)                       \
        _Pragma("unroll") for (int mf_ = 0; mf_ < 4; ++mf_) {                 \
      iacc[mf_][nf_] = __builtin_amdgcn_mfma_i32_16x16x64_i8(                 \
          aF[mf_][1], bF[nf_][1], iacc[mf_][nf_], 0, 0, 0);                   \
    }                                                                         \
    __builtin_amdgcn_s_setprio(0);                                            \
    __builtin_amdgcn_sched_barrier(0);                                        \
    asm volatile("s_waitcnt vmcnt(8)" ::: "memory");                          \
    __builtin_amdgcn_s_barrier();                                             \
  } while (0)

__global__ __launch_bounds__(256, 2) void k_gemm_i8(
    const int8_t* __restrict__ xq,   // [TOKENS][IN_F]
    const int8_t* __restrict__ wq,   // [OUT_F][IN_F]
    const float* __restrict__ sw,    // [OUT_F]
    const float* __restrict__ xs,    // [TOKENS]
    const float* __restrict__ bias,  // [OUT_F]
    float* __restrict__ out) {       // [TOKENS][OUT_F]
  extern __shared__ __align__(16) char smem[];  // 65536 B

  // XCD map: xcd OWNS bn range xcd*4..+3 (512 cols, 2 MB B-slice);
  // bm sweeps slowly (4 consecutive slots share each A-panel via L2).
  const int bidx = blockIdx.x;
  const int xcd = bidx & 7;
  const int slot = bidx >> 3;           // 0..255
  const int bm = slot >> 2;             // 0..63
  const int bn = xcd * 4 + (slot & 3);  // 0..31
  const int m0 = bm * 128;
  const int n0 = bn * 128;

  const int t = threadIdx.x;
  const int lane = t & 63;
  const int wid = t >> 6;    // 4 waves
  const int wr = wid >> 1;   // 2 (M)
  const int wc = wid & 1;    // 2 (N)
  const int fr = lane & 15;
  const int hq = lane >> 4;  // k-quarter (16 int8)

  const int csw0 = (hq ^ (fr & 7)) * 16;
  const int csw1 = ((hq ^ 4) ^ (fr & 7)) * 16;

  // staging: A 16KB = 16 instr (4/wave), B 16KB = 16 instr (4/wave)
  int goffS[4], ldsS[4];
#pragma unroll
  for (int i = 0; i < 4; ++i) {
    const int srow = wid * 32 + i * 8 + (lane >> 3);  // 0..127
    const int sch = (lane & 7) ^ (srow & 7);          // inverse swizzle
    goffS[i] = srow * IN_F + sch * 16;
    ldsS[i] = (wid * 4 + i) * 1024;                   // wave-uniform
  }

  const char* Ag = (const char*)(xq + (size_t)m0 * IN_F);
  const char* Bg = (const char*)(wq + (size_t)n0 * IN_F);

  i32x4 iacc[4][4];
#pragma unroll
  for (int i = 0; i < 4; ++i)
#pragma unroll
    for (int j = 0; j < 4; ++j) iacc[i][j] = (i32x4){0, 0, 0, 0};

  i32x4 aF[4][2];
  i32x4 bF[4][2];

  // ---- prologue: stage tiles 0 (buf0), 1 (buf1); drain tile0.
  STAGE_T(0, 0);
  STAGE_T(1, 1);
  asm volatile("s_waitcnt vmcnt(8) lgkmcnt(0)" ::: "memory");
  __builtin_amdgcn_s_barrier();

  // ---- main loop: 32 K-tiles, bufs alternate.
#pragma unroll 1
  for (int it = 0; it < 16; ++it) {
    const int T = 2 * it;
    PHASE(0, T);
    PHASE(1, T + 1);
  }

  // ---- epilogue: out = xs[m]*Sw[n]*acc + bias[n]
  float swv[4], bv[4];
#pragma unroll
  for (int nf = 0; nf < 4; ++nf) {
    const int n = n0 + wc * 64 + nf * 16 + fr;
    swv[nf] = sw[n];
    bv[nf] = bias[n];
  }
#pragma unroll
  for (int mf = 0; mf < 4; ++mf) {
#pragma unroll
    for (int r = 0; r < 4; ++r) {
      const int m = m0 + wr * 64 + mf * 16 + hq * 4 + r;
      const float xsv = xs[m];
      float* o = out + (size_t)m * OUT_F + n0;
#pragma unroll
      for (int nf = 0; nf < 4; ++nf) {
        o[wc * 64 + nf * 16 + fr] =
            xsv * swv[nf] * (float)iacc[mf][nf][r] + bv[nf];
      }
    }
  }
}

// ---------------------------------------------------------------------------
extern "C" void kernel_launch(void* const* d_in, const int* in_sizes, int n_in,
                              void* d_out, int out_size, void* d_ws,
                              size_t ws_size, hipStream_t stream) {
  const float* x = (const float*)d_in[0];
  const int* qweight = (const int*)d_in[1];
  const int* qzeros = (const int*)d_in[2];
  const float* scales = (const float*)d_in[3];
  const float* bias = (const float*)d_in[4];
  float* out = (float*)d_out;

  int8_t* xq = (int8_t*)d_ws;                       // 32 MiB
  int8_t* wq = xq + (size_t)TOKENS * IN_F;          // +16 MiB
  float* xs = (float*)(wq + (size_t)OUT_F * IN_F);  // +32 KiB
  float* sw = xs + TOKENS;                          // +16 KiB

  (void)hipFuncSetAttribute(reinterpret_cast<const void*>(&k_gemm_i8),
                            hipFuncAttributeMaxDynamicSharedMemorySize, 65536);

  // fused prep: 256 requant blocks (first) + 8192 quant blocks, concurrent
  k_prep<<<256 + TOKENS, 256, 33024, stream>>>(x, xq, xs, qweight, qzeros,
                                               scales, wq, sw);
  k_gemm_i8<<<(TOKENS / 128) * (OUT_F / 128), 256, 65536, stream>>>(
      xq, wq, sw, xs, bias, out);
}

// Round 22
// 175.961 us; speedup vs baseline: 1.2611x; 1.0916x over previous
//
#include <hip/hip_runtime.h>
#include <hip/hip_bf16.h>
#include <stdint.h>

#define TOKENS 8192
#define IN_F   4096
#define OUT_F  4096
#define GROUP  128

typedef __attribute__((ext_vector_type(4))) int   i32x4;
typedef __attribute__((ext_vector_type(4))) float f32x4;

// ---------------------------------------------------------------------------
// Kernel 1 (fused prep): blocks 0..255 requantize W (VALU-bound, coalesced
// wq writes via LDS transpose); blocks 256..8447 quantize x (HBM-bound).
// r22 fix: staging shrunk to 4 passes x 1024 k -> 16.6 KB LDS/block ->
// 9 blocks/CU, so the quant branch keeps its full 8-block (wave-limited)
// occupancy (r21's 33 KB capped it at 4 -> prep 44->57 us regression).
// ---------------------------------------------------------------------------
__global__ __launch_bounds__(256) void k_prep(
    const float* __restrict__ x, int8_t* __restrict__ xq,
    float* __restrict__ xs, const int* __restrict__ qweight,
    const int* __restrict__ qzeros, const float* __restrict__ scales,
    int8_t* __restrict__ wq, float* __restrict__ sw) {
  extern __shared__ __align__(16) char tile[];  // 16640 B (requant staging)
  __shared__ float smax[16][17];                // requant reduce
  __shared__ float red[4];                      // quant reduce
  const int bid = blockIdx.x;
  const int t = threadIdx.x;

  if (bid < 256) {
    // ---- requant: Sw[n] = max_g s_g[n]*max(z_g,15-z_g)/127 (no clip);
    //      wq[n][k] = round(s_g*(w-z_g)/Sw[n]) in [-127,127]
    const int n0 = bid * 16;
    const int col = t & 15;
    const int seg = t >> 4;  // 0..15
    const int n = n0 + col;

    // Sw = column max over all 32 groups (seg covers groups 2seg, 2seg+1)
    float m = 0.f;
#pragma unroll
    for (int i = 0; i < 2; ++i) {
      const int g = seg * 2 + i;
      const unsigned zw =
          ((const unsigned*)qzeros)[(size_t)g * (OUT_F / 8) + (n >> 3)];
      const int z = (int)((zw >> ((n & 7) * 4)) & 15u);
      const float s = scales[(size_t)g * OUT_F + n];
      m = fmaxf(m, s * (float)(z > 15 - z ? z : 15 - z));
    }
    smax[col][seg] = m;
    __syncthreads();
    float Sw = 0.f;
#pragma unroll
    for (int ss = 0; ss < 16; ++ss) Sw = fmaxf(Sw, smax[col][ss]);
    Sw /= 127.f;  // > 0 always
    if (seg == 0) sw[n] = Sw;
    const float inv = 1.f / Sw;

    // 4 passes of 8 groups (1024 k) each: compute -> LDS -> coalesced out.
    // Thread (col,seg) pass p: group g = p*8 + (seg>>1), words
    // (seg&1)*8 + kw (kw=0..7) -> k_local = seg*64 + kw*8 (bijective).
#pragma unroll
    for (int p = 0; p < 4; ++p) {
      const int g = p * 8 + (seg >> 1);
      const unsigned zw =
          ((const unsigned*)qzeros)[(size_t)g * (OUT_F / 8) + (n >> 3)];
      const int z = (int)((zw >> ((n & 7) * 4)) & 15u);
      const float f = scales[(size_t)g * OUT_F + n] * inv;
#pragma unroll
      for (int kw = 0; kw < 8; ++kw) {
        const int word = g * 16 + (seg & 1) * 8 + kw;
        const unsigned w = ((const unsigned*)qweight)[(size_t)word * OUT_F + n];
        unsigned lo = 0, hi = 0;
#pragma unroll
        for (int j = 0; j < 8; ++j) {
          const int q = (int)((w >> (4 * j)) & 15u);
          const int v = __float2int_rn(f * (float)(q - z));
          const unsigned b = (unsigned)(v & 255);
          if (j < 4)
            lo |= b << (8 * j);
          else
            hi |= b << (8 * (j - 4));
        }
        uint2 pk = {lo, hi};
        *(uint2*)(tile + col * 1040 + seg * 64 + kw * 8) = pk;
      }
      __syncthreads();
      // coalesced write-out: row = t>>4, j = t&15; 64 B per thread,
      // 1024 B contiguous per row.
      {
        const int row = t >> 4;
        const int j = t & 15;
        int8_t* dst = wq + (size_t)(n0 + row) * IN_F + p * 1024 + j * 64;
        const char* src = tile + row * 1040 + j * 64;
#pragma unroll
        for (int i = 0; i < 4; ++i) {
          *(i32x4*)(dst + i * 16) = *(const i32x4*)(src + i * 16);
        }
      }
      __syncthreads();
    }
  } else {
    // ---- quant_x: per-token absmax scale, x ~ xs[m]*xq
    const int row = bid - 256;
    const float4* xr = (const float4*)(x + (size_t)row * IN_F) + t * 4;
    float f[16];
    *(float4*)&f[0] = xr[0];
    *(float4*)&f[4] = xr[1];
    *(float4*)&f[8] = xr[2];
    *(float4*)&f[12] = xr[3];
    float am = 0.f;
#pragma unroll
    for (int j = 0; j < 16; ++j) am = fmaxf(am, fabsf(f[j]));
#pragma unroll
    for (int off = 32; off; off >>= 1) am = fmaxf(am, __shfl_xor(am, off));
    if ((t & 63) == 0) red[t >> 6] = am;
    __syncthreads();
    am = fmaxf(fmaxf(red[0], red[1]), fmaxf(red[2], red[3]));
    am = fmaxf(am, 1e-8f);
    const float inv = 127.f / am;
    if (t == 0) xs[row] = am / 127.f;
    union {
      i32x4 v;
      int8_t c[16];
    } u;
#pragma unroll
    for (int j = 0; j < 16; ++j) u.c[j] = (int8_t)__float2int_rn(f[j] * inv);
    ((i32x4*)(xq + (size_t)row * IN_F))[t] = u.v;
  }
}

// ---------------------------------------------------------------------------
// Kernel 2: PURE int8 MFMA GEMM — round-15/19/21 configuration (measured
// best: 135 us, MfmaUtil ~50, 0 bank conflicts). Structural sweep complete:
// r14 166 / r16 143.6 / r17 165.7 / r18 151 / r20 177.5 all worse.
// Block 128x128, 4 waves (2x2), wave tile 64x64, BK=128.
// LDS = 2 bufs x (A16K + B16K) = 64 KB -> 2 blocks/CU; regs ~148/wave.
// Per phase (WAR invariant): 16 ds_reads -> lgkm(0) -> barrier ->
// STAGE T+2 (same buf) -> 32 MFMA -> vmcnt(8) -> barrier.
// XCD map: xcd owns 4 bn (512 cols, 2 MB B-slice L2-resident); bm streams.
// Epilogue: out = xs[m]*Sw[n]*acc + bias[n].
// ---------------------------------------------------------------------------
__device__ inline void gload_lds16(const void* g, void* l) {
  __builtin_amdgcn_global_load_lds(
      (const __attribute__((address_space(1))) void*)g,
      (__attribute__((address_space(3))) void*)l, 16, 0, 0);
}

#define STAGE_T(buf, tile)                                                    \
  do {                                                                        \
    _Pragma("unroll") for (int i_ = 0; i_ < 4; ++i_) {                        \
      gload_lds16(Ag + goffS[i_] + (size_t)((tile) & 31) * 128,               \
                  smem + (buf)*32768 + ldsS[i_]);                             \
    }                                                                         \
    _Pragma("unroll") for (int i_ = 0; i_ < 4; ++i_) {                        \
      gload_lds16(Bg + goffS[i_] + (size_t)((tile) & 31) * 128,               \
                  smem + (buf)*32768 + 16384 + ldsS[i_]);                     \
    }                                                                         \
  } while (0)

#define PHASE(bufc, T)                                                        \
  do {                                                                        \
    _Pragma("unroll") for (int nf_ = 0; nf_ < 4; ++nf_) {                     \
      const char* p_ =                                                        \
          smem + (bufc)*32768 + 16384 + (wc * 64 + nf_ * 16 + fr) * 128;      \
      bF[nf_][0] = *(const i32x4*)(p_ + csw0);                                \
      bF[nf_][1] = *(const i32x4*)(p_ + csw1);                                \
    }                                                                         \
    _Pragma("unroll") for (int mf_ = 0; mf_ < 4; ++mf_) {                     \
      const char* p_ = smem + (bufc)*32768 + (wr * 64 + mf_ * 16 + fr) * 128; \
      aF[mf_][0] = *(const i32x4*)(p_ + csw0);                                \
      aF[mf_][1] = *(const i32x4*)(p_ + csw1);                                \
    }                                                                         \
    asm volatile("s_waitcnt lgkmcnt(0)" ::: "memory");                        \
    __builtin_amdgcn_sched_barrier(0);                                        \
    __builtin_amdgcn_s_barrier(); /* all waves' reads of bufc done */         \
    STAGE_T(bufc, (T) + 2);       /* safe to overwrite bufc now */            \
    __builtin_amdgcn_s_setprio(1);                                            \
    _Pragma("unroll") for (int nf_ = 0; nf_ < 4; ++nf_)                       \
        _Pragma("unroll") for (int mf_ = 0; mf_ < 4; ++mf_) {                 \
      iacc[mf_][nf_] = __builtin_amdgcn_mfma_i32_16x16x64_i8(                 \
          aF[mf_][0], bF[nf_][0], iacc[mf_][nf_], 0, 0, 0);                   \
    }                                                                         \
    _Pragma("unroll") for (int nf_ = 0; nf_ < 4; ++nf_)                       \
        _Pragma("unroll") for (int mf_ = 0; mf_ < 4; ++mf_) {                 \
      iacc[mf_][nf_] = __builtin_amdgcn_mfma_i32_16x16x64_i8(                 \
          aF[mf_][1], bF[nf_][1], iacc[mf_][nf_], 0, 0, 0);                   \
    }                                                                         \
    __builtin_amdgcn_s_setprio(0);                                            \
    __builtin_amdgcn_sched_barrier(0);                                        \
    asm volatile("s_waitcnt vmcnt(8)" ::: "memory");                          \
    __builtin_amdgcn_s_barrier();                                             \
  } while (0)

__global__ __launch_bounds__(256, 2) void k_gemm_i8(
    const int8_t* __restrict__ xq,   // [TOKENS][IN_F]
    const int8_t* __restrict__ wq,   // [OUT_F][IN_F]
    const float* __restrict__ sw,    // [OUT_F]
    const float* __restrict__ xs,    // [TOKENS]
    const float* __restrict__ bias,  // [OUT_F]
    float* __restrict__ out) {       // [TOKENS][OUT_F]
  extern __shared__ __align__(16) char smem[];  // 65536 B

  // XCD map: xcd OWNS bn range xcd*4..+3 (512 cols, 2 MB B-slice);
  // bm sweeps slowly (4 consecutive slots share each A-panel via L2).
  const int bidx = blockIdx.x;
  const int xcd = bidx & 7;
  const int slot = bidx >> 3;           // 0..255
  const int bm = slot >> 2;             // 0..63
  const int bn = xcd * 4 + (slot & 3);  // 0..31
  const int m0 = bm * 128;
  const int n0 = bn * 128;

  const int t = threadIdx.x;
  const int lane = t & 63;
  const int wid = t >> 6;    // 4 waves
  const int wr = wid >> 1;   // 2 (M)
  const int wc = wid & 1;    // 2 (N)
  const int fr = lane & 15;
  const int hq = lane >> 4;  // k-quarter (16 int8)

  const int csw0 = (hq ^ (fr & 7)) * 16;
  const int csw1 = ((hq ^ 4) ^ (fr & 7)) * 16;

  // staging: A 16KB = 16 instr (4/wave), B 16KB = 16 instr (4/wave)
  int goffS[4], ldsS[4];
#pragma unroll
  for (int i = 0; i < 4; ++i) {
    const int srow = wid * 32 + i * 8 + (lane >> 3);  // 0..127
    const int sch = (lane & 7) ^ (srow & 7);          // inverse swizzle
    goffS[i] = srow * IN_F + sch * 16;
    ldsS[i] = (wid * 4 + i) * 1024;                   // wave-uniform
  }

  const char* Ag = (const char*)(xq + (size_t)m0 * IN_F);
  const char* Bg = (const char*)(wq + (size_t)n0 * IN_F);

  i32x4 iacc[4][4];
#pragma unroll
  for (int i = 0; i < 4; ++i)
#pragma unroll
    for (int j = 0; j < 4; ++j) iacc[i][j] = (i32x4){0, 0, 0, 0};

  i32x4 aF[4][2];
  i32x4 bF[4][2];

  // ---- prologue: stage tiles 0 (buf0), 1 (buf1); drain tile0.
  STAGE_T(0, 0);
  STAGE_T(1, 1);
  asm volatile("s_waitcnt vmcnt(8) lgkmcnt(0)" ::: "memory");
  __builtin_amdgcn_s_barrier();

  // ---- main loop: 32 K-tiles, bufs alternate.
#pragma unroll 1
  for (int it = 0; it < 16; ++it) {
    const int T = 2 * it;
    PHASE(0, T);
    PHASE(1, T + 1);
  }

  // ---- epilogue: out = xs[m]*Sw[n]*acc + bias[n]
  float swv[4], bv[4];
#pragma unroll
  for (int nf = 0; nf < 4; ++nf) {
    const int n = n0 + wc * 64 + nf * 16 + fr;
    swv[nf] = sw[n];
    bv[nf] = bias[n];
  }
#pragma unroll
  for (int mf = 0; mf < 4; ++mf) {
#pragma unroll
    for (int r = 0; r < 4; ++r) {
      const int m = m0 + wr * 64 + mf * 16 + hq * 4 + r;
      const float xsv = xs[m];
      float* o = out + (size_t)m * OUT_F + n0;
#pragma unroll
      for (int nf = 0; nf < 4; ++nf) {
        o[wc * 64 + nf * 16 + fr] =
            xsv * swv[nf] * (float)iacc[mf][nf][r] + bv[nf];
      }
    }
  }
}

// ---------------------------------------------------------------------------
extern "C" void kernel_launch(void* const* d_in, const int* in_sizes, int n_in,
                              void* d_out, int out_size, void* d_ws,
                              size_t ws_size, hipStream_t stream) {
  const float* x = (const float*)d_in[0];
  const int* qweight = (const int*)d_in[1];
  const int* qzeros = (const int*)d_in[2];
  const float* scales = (const float*)d_in[3];
  const float* bias = (const float*)d_in[4];
  float* out = (float*)d_out;

  int8_t* xq = (int8_t*)d_ws;                       // 32 MiB
  int8_t* wq = xq + (size_t)TOKENS * IN_F;          // +16 MiB
  float* xs = (float*)(wq + (size_t)OUT_F * IN_F);  // +32 KiB
  float* sw = xs + TOKENS;                          // +16 KiB

  (void)hipFuncSetAttribute(reinterpret_cast<const void*>(&k_gemm_i8),
                            hipFuncAttributeMaxDynamicSharedMemorySize, 65536);

  // fused prep: 256 requant blocks (first) + 8192 quant blocks, concurrent
  k_prep<<<256 + TOKENS, 256, 16640, stream>>>(x, xq, xs, qweight, qzeros,
                                               scales, wq, sw);
  k_gemm_i8<<<(TOKENS / 128) * (OUT_F / 128), 256, 65536, stream>>>(
      xq, wq, sw, xs, bias, out);
}